// Round 6
// baseline (840.743 us; speedup 1.0000x reference)
//
#include <hip/hip_runtime.h>

#define NODES 50000
#define FEAT  256
#define RELS  4
#define EDGES 80000
#define NEDGE (RELS * EDGES)      // 320000
#define NBLKS 391                 // ceil(50000/128)
#define NBKT  (NBLKS * RELS)      // 1564 buckets
#define SCAN_N 2048

#define AROWS 128
#define ASTR  260                 // f32 stride; proven conflict-benign in R5
#define ABLK  512

typedef __bf16 bf16x8  __attribute__((ext_vector_type(8)));
typedef float  floatx4 __attribute__((ext_vector_type(4)));

struct BF8U { union { unsigned short u[8]; bf16x8 v; uint4 q; }; };

static __device__ __forceinline__ unsigned short f2bf(float f) {
  union { float f; unsigned u; } v; v.f = f;
  unsigned r = v.u + 0x7FFFu + ((v.u >> 16) & 1u);   // RNE
  return (unsigned short)(r >> 16);
}
static __device__ __forceinline__ bf16x8 cvt8(const float* p, float s) {
  float4 a = ((const float4*)p)[0], b = ((const float4*)p)[1];
  BF8U r;
  r.u[0] = f2bf(a.x * s); r.u[1] = f2bf(a.y * s);
  r.u[2] = f2bf(a.z * s); r.u[3] = f2bf(a.w * s);
  r.u[4] = f2bf(b.x * s); r.u[5] = f2bf(b.y * s);
  r.u[6] = f2bf(b.z * s); r.u[7] = f2bf(b.w * s);
  return r.v;
}

// ===========================================================================
// Setup kernels (workspace total: 1,959,936 B)
__global__ __launch_bounds__(256) void zero_kernel(unsigned* __restrict__ cnt) {
  int i = blockIdx.x * 256 + threadIdx.x;
  if (i < SCAN_N) cnt[i] = 0u;
}

__global__ __launch_bounds__(256) void count_kernel(const int* __restrict__ dst,
                                                    unsigned* __restrict__ cnt) {
  int e = blockIdx.x * 256 + threadIdx.x;
  if (e < NEDGE) {
    int r = e / EDGES;
    atomicAdd(&cnt[(unsigned)(dst[e] >> 7) * RELS + r], 1u);
  }
}

// single-block exclusive scan of cnt[0..NBKT) -> off[0..NBKT], cur = off copy
__global__ __launch_bounds__(256) void scan_kernel(const unsigned* __restrict__ cnt,
                                                   unsigned* __restrict__ off,
                                                   unsigned* __restrict__ cur) {
  __shared__ unsigned sa[SCAN_N], sb[SCAN_N];
  for (int i = threadIdx.x; i < SCAN_N; i += 256) sa[i] = (i < NBKT) ? cnt[i] : 0u;
  __syncthreads();
  unsigned* pin = sa; unsigned* pout = sb;
  for (int d = 1; d < SCAN_N; d <<= 1) {
    for (int i = threadIdx.x; i < SCAN_N; i += 256)
      pout[i] = pin[i] + ((i >= d) ? pin[i - d] : 0u);
    __syncthreads();
    unsigned* t = pin; pin = pout; pout = t;
  }
  for (int i = threadIdx.x; i <= NBKT; i += 256) {      // pin = inclusive scan
    unsigned v = (i == 0) ? 0u : pin[i - 1];
    off[i] = v;
    if (i < NBKT) cur[i] = v;
  }
}

__global__ __launch_bounds__(256) void fill_kernel(const int* __restrict__ src,
                                                   const int* __restrict__ dst,
                                                   unsigned* __restrict__ cur,
                                                   unsigned* __restrict__ epk) {
  int e = blockIdx.x * 256 + threadIdx.x;
  if (e < NEDGE) {
    int r = e / EDGES, d = dst[e];
    unsigned pos = atomicAdd(&cur[(unsigned)(d >> 7) * RELS + r], 1u);
    epk[pos] = ((unsigned)src[e] << 7) | (unsigned)(d & 127);
  }
}

// W (f32) -> bf16 fragment order; uint4 slot g = kcg*1024 + nc*64 + lane:
// val j = B[kcg*32 + (lane>>4)*8 + j][nc*16 + (lane&15)], B = [W0;W1;W2;W3;Wself]
__global__ __launch_bounds__(256) void prepack_kernel(const float* __restrict__ w,
                                                      const float* __restrict__ sw,
                                                      unsigned short* __restrict__ bpk) {
  int t = blockIdx.x * 256 + threadIdx.x;      // [0, 40960)
  int ln = t & 63, nc = (t >> 6) & 15, kcg = t >> 10;
  int col = nc * 16 + (ln & 15);
  int row0 = kcg * 32 + (ln >> 4) * 8;
  BF8U vv;
#pragma unroll
  for (int j = 0; j < 8; ++j) {
    int gk = row0 + j;
    int c = gk >> 8, kr = gk & 255;
    const float* sp = (c < 4) ? (w + (size_t)c * 65536) : sw;
    vv.u[j] = f2bf(sp[(size_t)kr * 256 + col]);
  }
  ((uint4*)bpk)[t] = vv.q;
}

// ===========================================================================
// Main kernel: 128 rows/block, 512 thr (8 waves x 16 rows), f32 LDS agg.
__global__ __launch_bounds__(ABLK) void rgcn_main(
    const float* __restrict__ x, const unsigned* __restrict__ off,
    const unsigned* __restrict__ epk, const unsigned short* __restrict__ bpk,
    const float* __restrict__ bias, float* __restrict__ out) {
  __shared__ float sAgg[AROWS * ASTR];          // 133120 B
  __shared__ unsigned short sB[8192];           //  16384 B
  __shared__ unsigned sDeg[AROWS];              //    512 B

  const int tid = threadIdx.x, wave = tid >> 6, lane = tid & 63;
  const int quad = lane >> 4, l15 = lane & 15;
  const int m0 = blockIdx.x * AROWS;
  const int wrow = wave * 16;

  floatx4 acc[16] = {};
  const floatx4 fz = {0.f, 0.f, 0.f, 0.f};

  for (int r = 0; r < RELS; ++r) {
    for (int t = tid; t < (AROWS * ASTR) / 4; t += ABLK) ((floatx4*)sAgg)[t] = fz;
    if (tid < AROWS) sDeg[tid] = 0u;
    __syncthreads();

    // scatter: only this bucket's edges (avg ~205), one edge per wave-iter
    unsigned lo = off[blockIdx.x * RELS + r], hi = off[blockIdx.x * RELS + r + 1];
    for (unsigned e = lo + wave; e < hi; e += 8) {
      unsigned p = epk[e];
      int s = (int)(p >> 7), loc = (int)(p & 127u);
      if (lane == 0) atomicAdd(&sDeg[loc], 1u);
      const float* xp = x + (size_t)s * FEAT + lane;
      float* ap = sAgg + loc * ASTR + lane;
#pragma unroll
      for (int k = 0; k < 4; ++k) atomicAdd(ap + k * 64, xp[k * 64]);
    }
    __syncthreads();

    unsigned dg = sDeg[wrow + l15];
    float rs = 1.0f / (float)(dg ? dg : 1u);

    for (int kc = 0; kc < 8; ++kc) {
      const uint4* s4 = (const uint4*)bpk + (size_t)(r * 8 + kc) * 1024;
      ((uint4*)sB)[tid] = s4[tid];
      ((uint4*)sB)[tid + 512] = s4[tid + 512];
      __syncthreads();
      bf16x8 a = cvt8(&sAgg[(wrow + l15) * ASTR + kc * 32 + quad * 8], rs);
#pragma unroll
      for (int ns = 0; ns < 16; ++ns) {
        BF8U b8; b8.q = ((const uint4*)sB)[ns * 64 + lane];
        acc[ns] = __builtin_amdgcn_mfma_f32_16x16x32_bf16(a, b8.v, acc[ns], 0, 0, 0);
      }
      __syncthreads();
    }
  }

  // self-loop chunk (kcg 32..39): A = x rows directly
  {
    int row = m0 + wrow + l15;
    if (row >= NODES) row = NODES - 1;
    for (int kc = 0; kc < 8; ++kc) {
      const uint4* s4 = (const uint4*)bpk + (size_t)(32 + kc) * 1024;
      ((uint4*)sB)[tid] = s4[tid];
      ((uint4*)sB)[tid + 512] = s4[tid + 512];
      __syncthreads();
      bf16x8 a = cvt8(x + (size_t)row * FEAT + kc * 32 + quad * 8, 1.0f);
#pragma unroll
      for (int ns = 0; ns < 16; ++ns) {
        BF8U b8; b8.q = ((const uint4*)sB)[ns * 64 + lane];
        acc[ns] = __builtin_amdgcn_mfma_f32_16x16x32_bf16(a, b8.v, acc[ns], 0, 0, 0);
      }
      __syncthreads();
    }
  }

  // epilogue: C/D row = quad*4 + reg, col = lane&15  (f32 stores)
#pragma unroll
  for (int i = 0; i < 4; ++i) {
    int row = m0 + wrow + quad * 4 + i;
    if (row < NODES) {
      float* op = out + (size_t)row * FEAT;
#pragma unroll
      for (int ns = 0; ns < 16; ++ns) {
        int col = ns * 16 + l15;
        op[col] = fmaxf(acc[ns][i] + bias[col], 0.0f);
      }
    }
  }
}

// ===========================================================================
// Fallback (R5's proven kernel): used only if ws_size < 2 MB.
__global__ __launch_bounds__(ABLK) void rgcn_fallback(
    const float* __restrict__ x, const int* __restrict__ src,
    const int* __restrict__ dst, const float* __restrict__ w,
    const float* __restrict__ sw, const float* __restrict__ bias,
    float* __restrict__ out) {
  __shared__ float sAgg[AROWS * ASTR];
  __shared__ unsigned short sB[8192];
  __shared__ unsigned sDeg[AROWS];

  const int tid = threadIdx.x, wave = tid >> 6, lane = tid & 63;
  const int quad = lane >> 4, l15 = lane & 15;
  const int m0 = blockIdx.x * AROWS;
  const int wrow = wave * 16;

  floatx4 acc[16] = {};
  const floatx4 fz = {0.f, 0.f, 0.f, 0.f};

  for (int r = 0; r < RELS; ++r) {
    for (int t = tid; t < (AROWS * ASTR) / 4; t += ABLK) ((floatx4*)sAgg)[t] = fz;
    if (tid < AROWS) sDeg[tid] = 0u;
    __syncthreads();
    const int4* sr4 = (const int4*)(src + r * EDGES);
    const int4* dr4 = (const int4*)(dst + r * EDGES);
    for (int i0 = tid; i0 < 20480; i0 += ABLK) {
      int4 d4 = {-1, -1, -1, -1}, s4 = {0, 0, 0, 0};
      if (i0 < EDGES / 4) { d4 = dr4[i0]; s4 = sr4[i0]; }
      int dd[4] = {d4.x, d4.y, d4.z, d4.w};
      int ss[4] = {s4.x, s4.y, s4.z, s4.w};
#pragma unroll
      for (int j = 0; j < 4; ++j) {
        unsigned u = (unsigned)(dd[j] - m0);
        unsigned long long mb = __ballot(u < (unsigned)AROWS);
        while (mb) {
          int jl = (int)__ffsll(mb) - 1; mb &= mb - 1;
          int s = __shfl(ss[j], jl);
          int ul = __shfl((int)u, jl);
          if (lane == 0) atomicAdd(&sDeg[ul], 1u);
          const float* xp = x + (size_t)s * FEAT + lane;
          float* ap = sAgg + ul * ASTR + lane;
#pragma unroll
          for (int k = 0; k < 4; ++k) atomicAdd(ap + k * 64, xp[k * 64]);
        }
      }
    }
    __syncthreads();
    unsigned dg = sDeg[wrow + l15];
    float rs = 1.0f / (float)(dg ? dg : 1u);
    const float* Wc = w + (size_t)r * 65536;
    for (int kc = 0; kc < 8; ++kc) {
      for (int t = tid; t < 1024; t += ABLK) {
        int ln = t & 63, nc = t >> 6;
        const float* wp = Wc + (size_t)(kc * 32 + (ln >> 4) * 8) * 256 + nc * 16 + (ln & 15);
        BF8U vv;
#pragma unroll
        for (int j = 0; j < 8; ++j) vv.u[j] = f2bf(wp[(size_t)j * 256]);
        ((uint4*)sB)[t] = vv.q;
      }
      __syncthreads();
      bf16x8 a = cvt8(&sAgg[(wrow + l15) * ASTR + kc * 32 + quad * 8], rs);
#pragma unroll
      for (int ns = 0; ns < 16; ++ns) {
        BF8U b8; b8.q = ((const uint4*)sB)[ns * 64 + lane];
        acc[ns] = __builtin_amdgcn_mfma_f32_16x16x32_bf16(a, b8.v, acc[ns], 0, 0, 0);
      }
      __syncthreads();
    }
  }
  {
    int row = m0 + wrow + l15;
    if (row >= NODES) row = NODES - 1;
    for (int kc = 0; kc < 8; ++kc) {
      for (int t = tid; t < 1024; t += ABLK) {
        int ln = t & 63, nc = t >> 6;
        const float* wp = sw + (size_t)(kc * 32 + (ln >> 4) * 8) * 256 + nc * 16 + (ln & 15);
        BF8U vv;
#pragma unroll
        for (int j = 0; j < 8; ++j) vv.u[j] = f2bf(wp[(size_t)j * 256]);
        ((uint4*)sB)[t] = vv.q;
      }
      __syncthreads();
      bf16x8 a = cvt8(x + (size_t)row * FEAT + kc * 32 + quad * 8, 1.0f);
#pragma unroll
      for (int ns = 0; ns < 16; ++ns) {
        BF8U b8; b8.q = ((const uint4*)sB)[ns * 64 + lane];
        acc[ns] = __builtin_amdgcn_mfma_f32_16x16x32_bf16(a, b8.v, acc[ns], 0, 0, 0);
      }
      __syncthreads();
    }
  }
#pragma unroll
  for (int i = 0; i < 4; ++i) {
    int row = m0 + wrow + quad * 4 + i;
    if (row < NODES) {
      float* op = out + (size_t)row * FEAT;
#pragma unroll
      for (int ns = 0; ns < 16; ++ns) {
        int col = ns * 16 + l15;
        op[col] = fmaxf(acc[ns][i] + bias[col], 0.0f);
      }
    }
  }
}

// ===========================================================================
extern "C" void kernel_launch(void* const* d_in, const int* in_sizes, int n_in,
                              void* d_out, int out_size, void* d_ws, size_t ws_size,
                              hipStream_t stream) {
  const float* x    = (const float*)d_in[0];
  const int*   src  = (const int*)d_in[1];
  const int*   dst  = (const int*)d_in[2];
  const float* w    = (const float*)d_in[3];
  const float* sw   = (const float*)d_in[4];
  const float* bias = (const float*)d_in[5];
  float*       out  = (float*)d_out;
  char* ws = (char*)d_ws;

  // ws layout: bpk 655360 | cnt 8192 | off 8192 | cur 8192 | epk 1280000
  const size_t NEED = 1959936;
  if (ws_size >= NEED) {
    unsigned short* bpk = (unsigned short*)ws;
    unsigned* cnt = (unsigned*)(ws + 655360);
    unsigned* off = (unsigned*)(ws + 663552);
    unsigned* cur = (unsigned*)(ws + 671744);
    unsigned* epk = (unsigned*)(ws + 679936);

    zero_kernel<<<8, 256, 0, stream>>>(cnt);
    count_kernel<<<(NEDGE + 255) / 256, 256, 0, stream>>>(dst, cnt);
    scan_kernel<<<1, 256, 0, stream>>>(cnt, off, cur);
    fill_kernel<<<(NEDGE + 255) / 256, 256, 0, stream>>>(src, dst, cur, epk);
    prepack_kernel<<<160, 256, 0, stream>>>(w, sw, bpk);
    rgcn_main<<<NBLKS, ABLK, 0, stream>>>(x, off, epk, bpk, bias, out);
  } else {
    rgcn_fallback<<<NBLKS, ABLK, 0, stream>>>(x, src, dst, w, sw, bias, out);
  }
}

// Round 7
// 758.627 us; speedup vs baseline: 1.1082x; 1.1082x over previous
//
#include <hip/hip_runtime.h>

#define NODES 50000
#define FEAT  256
#define RELS  4
#define EDGES 80000
#define NEDGE (RELS * EDGES)      // 320000
#define NB    (RELS * NODES)      // 200000 CSR buckets
#define KSTEPS 40                 // K = 1280 = 40 * 32
#define CHUNKEL ((size_t)NODES * FEAT)

typedef __bf16 bf16x8  __attribute__((ext_vector_type(8)));
typedef float  floatx4 __attribute__((ext_vector_type(4)));

struct BF8U { union { unsigned short u[8]; bf16x8 v; uint4 q; }; };

static __device__ __forceinline__ unsigned short f2bf(float f) {
  union { float f; unsigned u; } v; v.f = f;
  unsigned r = v.u + 0x7FFFu + ((v.u >> 16) & 1u);   // RNE
  return (unsigned short)(r >> 16);
}
static __device__ __forceinline__ bf16x8 cvt8(const float* p, float s) {
  float4 a = ((const float4*)p)[0], b = ((const float4*)p)[1];
  BF8U r;
  r.u[0] = f2bf(a.x * s); r.u[1] = f2bf(a.y * s);
  r.u[2] = f2bf(a.z * s); r.u[3] = f2bf(a.w * s);
  r.u[4] = f2bf(b.x * s); r.u[5] = f2bf(b.y * s);
  r.u[6] = f2bf(b.z * s); r.u[7] = f2bf(b.w * s);
  return r.v;
}

// ===========================================================================
// Setup: CSR by bucket b = r*NODES + dst
__global__ __launch_bounds__(256) void zero_kernel(unsigned* __restrict__ cnt) {
  int i = blockIdx.x * 256 + threadIdx.x;
  if (i < NB) cnt[i] = 0u;
}

__global__ __launch_bounds__(256) void count_kernel(const int* __restrict__ dst,
                                                    unsigned* __restrict__ cnt) {
  int e = blockIdx.x * 256 + threadIdx.x;
  if (e < NEDGE) atomicAdd(&cnt[(e / EDGES) * NODES + dst[e]], 1u);
}

// single-block chunked exclusive scan over NB counters
__global__ __launch_bounds__(1024) void scan_kernel(const unsigned* __restrict__ cnt,
                                                    unsigned* __restrict__ off,
                                                    unsigned* __restrict__ cur) {
  __shared__ unsigned sa[1024], sb[1024];
  const int C = (NB + 1023) / 1024;            // 196
  int t = threadIdx.x;
  int a0 = t * C, a1 = a0 + C;
  if (a0 > NB) a0 = NB;
  if (a1 > NB) a1 = NB;
  unsigned s = 0;
  for (int i = a0; i < a1; ++i) s += cnt[i];
  sa[t] = s;
  __syncthreads();
  unsigned* pin = sa; unsigned* pout = sb;
  for (int d = 1; d < 1024; d <<= 1) {
    pout[t] = pin[t] + ((t >= d) ? pin[t - d] : 0u);
    __syncthreads();
    unsigned* tmp = pin; pin = pout; pout = tmp;
  }
  unsigned run = pin[t] - s;                   // exclusive prefix of this chunk
  for (int i = a0; i < a1; ++i) {
    off[i] = run; cur[i] = run; run += cnt[i];
  }
  if (a1 == NB) off[NB] = run;                 // all such threads write the total
}

__global__ __launch_bounds__(256) void fill_kernel(const int* __restrict__ src,
                                                   const int* __restrict__ dst,
                                                   unsigned* __restrict__ cur,
                                                   unsigned* __restrict__ epk) {
  int e = blockIdx.x * 256 + threadIdx.x;
  if (e < NEDGE) {
    int r = e / EDGES;
    unsigned pos = atomicAdd(&cur[r * NODES + dst[e]], 1u);
    epk[pos] = (unsigned)src[e];
  }
}

// W (f32) -> bf16 fragment order; uint4 slot g = kc*1024 + nc*64 + lane:
// val j = B[kc*32 + (lane>>4)*8 + j][nc*16 + (lane&15)], B = [W0;W1;W2;W3;Wself]
__global__ __launch_bounds__(256) void prepack_kernel(const float* __restrict__ w,
                                                      const float* __restrict__ sw,
                                                      unsigned short* __restrict__ bpk) {
  int t = blockIdx.x * 256 + threadIdx.x;      // [0, 40960)
  int ln = t & 63, nc = (t >> 6) & 15, kc = t >> 10;
  int col = nc * 16 + (ln & 15);
  int row0 = kc * 32 + (ln >> 4) * 8;
  BF8U vv;
#pragma unroll
  for (int j = 0; j < 8; ++j) {
    int gk = row0 + j;
    int c = gk >> 8, kr = gk & 255;
    const float* sp = (c < 4) ? (w + (size_t)c * 65536) : sw;
    vv.u[j] = f2bf(sp[(size_t)kr * 256 + col]);
  }
  ((uint4*)bpk)[t] = vv.q;
}

// ===========================================================================
// Gather: one wave per node; VGPR accumulation, no atomics, no LDS, no syncs.
__global__ __launch_bounds__(256) void gather_kernel(
    const float* __restrict__ x, const unsigned* __restrict__ off,
    const unsigned* __restrict__ epk, unsigned short* __restrict__ agg) {
  int n = blockIdx.x * 4 + (threadIdx.x >> 6);
  int lane = threadIdx.x & 63;
  if (n >= NODES) return;
  for (int r = 0; r < RELS; ++r) {
    unsigned b = (unsigned)r * NODES + n;
    unsigned lo = off[b], hi = off[b + 1];
    float4 acc = {0.f, 0.f, 0.f, 0.f};
    for (unsigned e = lo; e < hi; ++e) {
      int s = (int)epk[e];
      float4 v = *(const float4*)(x + (size_t)s * FEAT + lane * 4);
      acc.x += v.x; acc.y += v.y; acc.z += v.z; acc.w += v.w;
    }
    unsigned dg = hi - lo;
    float sc = 1.0f / (float)(dg ? dg : 1u);
    unsigned short o[4] = { f2bf(acc.x * sc), f2bf(acc.y * sc),
                            f2bf(acc.z * sc), f2bf(acc.w * sc) };
    *(uint2*)(agg + (size_t)b * FEAT + lane * 4) = *(const uint2*)o;
  }
}

// ===========================================================================
// GEMM: C[50000,256] = [agg0..3 | x] @ Bpk + bias, relu. LDS-free.
// 782 blocks (391 x 2) x 256 thr = 4 waves; wave tile 64x64 (4x4 MFMA).
__global__ __launch_bounds__(256) void gemm_kernel(
    const unsigned short* __restrict__ agg, const float* __restrict__ x,
    const unsigned short* __restrict__ bpk, const float* __restrict__ bias,
    float* __restrict__ out) {
  int lane = threadIdx.x & 63, wave = threadIdx.x >> 6;
  int quad = lane >> 4, l15 = lane & 15;
  int m0 = blockIdx.x * 128 + (wave >> 1) * 64;
  int nbase = blockIdx.y * 8 + (wave & 1) * 4;      // nc index base
  int n0 = nbase * 16;

  int rows[4];
#pragma unroll
  for (int ms = 0; ms < 4; ++ms) {
    int r = m0 + ms * 16 + l15;
    rows[ms] = (r < NODES) ? r : (NODES - 1);       // dup; stores guarded
  }

  floatx4 acc[4][4] = {};
  const uint4* bp4 = (const uint4*)bpk;

  for (int kc = 0; kc < KSTEPS; ++kc) {
    int c = kc >> 3;
    int kk = (kc & 7) * 32 + quad * 8;
    bf16x8 a[4], b[4];
    if (c < 4) {
      const unsigned short* ab = agg + (size_t)c * CHUNKEL;
#pragma unroll
      for (int ms = 0; ms < 4; ++ms) {
        BF8U t; t.q = *(const uint4*)(ab + (size_t)rows[ms] * FEAT + kk);
        a[ms] = t.v;
      }
    } else {
#pragma unroll
      for (int ms = 0; ms < 4; ++ms)
        a[ms] = cvt8(x + (size_t)rows[ms] * FEAT + kk, 1.0f);
    }
#pragma unroll
    for (int ns = 0; ns < 4; ++ns) {
      BF8U t; t.q = bp4[(size_t)kc * 1024 + (nbase + ns) * 64 + lane];
      b[ns] = t.v;
    }
#pragma unroll
    for (int ms = 0; ms < 4; ++ms)
#pragma unroll
      for (int ns = 0; ns < 4; ++ns)
        acc[ms][ns] = __builtin_amdgcn_mfma_f32_16x16x32_bf16(a[ms], b[ns], acc[ms][ns], 0, 0, 0);
  }

  // epilogue: C/D row = quad*4 + i, col = l15 (proven)
#pragma unroll
  for (int ms = 0; ms < 4; ++ms)
#pragma unroll
    for (int i = 0; i < 4; ++i) {
      int row = m0 + ms * 16 + quad * 4 + i;
      if (row < NODES) {
        float* op = out + (size_t)row * FEAT + n0;
#pragma unroll
        for (int ns = 0; ns < 4; ++ns) {
          int col = ns * 16 + l15;
          op[col] = fmaxf(acc[ms][ns][i] + bias[n0 + col], 0.0f);
        }
      }
    }
}

// ===========================================================================
// Fallback (R5's proven monolith) — only if ws_size too small.
#define AROWS 128
#define ASTR  260
#define ABLK  512

__global__ __launch_bounds__(ABLK) void rgcn_fallback(
    const float* __restrict__ x, const int* __restrict__ src,
    const int* __restrict__ dst, const float* __restrict__ w,
    const float* __restrict__ sw, const float* __restrict__ bias,
    float* __restrict__ out) {
  __shared__ float sAgg[AROWS * ASTR];
  __shared__ unsigned short sB[8192];
  __shared__ unsigned sDeg[AROWS];
  const int tid = threadIdx.x, wave = tid >> 6, lane = tid & 63;
  const int quad = lane >> 4, l15 = lane & 15;
  const int m0 = blockIdx.x * AROWS;
  const int wrow = wave * 16;
  floatx4 acc[16] = {};
  const floatx4 fz = {0.f, 0.f, 0.f, 0.f};
  for (int r = 0; r < RELS; ++r) {
    for (int t = tid; t < (AROWS * ASTR) / 4; t += ABLK) ((floatx4*)sAgg)[t] = fz;
    if (tid < AROWS) sDeg[tid] = 0u;
    __syncthreads();
    const int4* sr4 = (const int4*)(src + r * EDGES);
    const int4* dr4 = (const int4*)(dst + r * EDGES);
    for (int i0 = tid; i0 < 20480; i0 += ABLK) {
      int4 d4 = {-1, -1, -1, -1}, s4 = {0, 0, 0, 0};
      if (i0 < EDGES / 4) { d4 = dr4[i0]; s4 = sr4[i0]; }
      int dd[4] = {d4.x, d4.y, d4.z, d4.w};
      int ss[4] = {s4.x, s4.y, s4.z, s4.w};
#pragma unroll
      for (int j = 0; j < 4; ++j) {
        unsigned u = (unsigned)(dd[j] - m0);
        unsigned long long mb = __ballot(u < (unsigned)AROWS);
        while (mb) {
          int jl = (int)__ffsll(mb) - 1; mb &= mb - 1;
          int s = __shfl(ss[j], jl);
          int ul = __shfl((int)u, jl);
          if (lane == 0) atomicAdd(&sDeg[ul], 1u);
          const float* xp = x + (size_t)s * FEAT + lane;
          float* ap = sAgg + ul * ASTR + lane;
#pragma unroll
          for (int k = 0; k < 4; ++k) atomicAdd(ap + k * 64, xp[k * 64]);
        }
      }
    }
    __syncthreads();
    unsigned dg = sDeg[wrow + l15];
    float rs = 1.0f / (float)(dg ? dg : 1u);
    const float* Wc = w + (size_t)r * 65536;
    for (int kc = 0; kc < 8; ++kc) {
      for (int t = tid; t < 1024; t += ABLK) {
        int ln = t & 63, nc = t >> 6;
        const float* wp = Wc + (size_t)(kc * 32 + (ln >> 4) * 8) * 256 + nc * 16 + (ln & 15);
        BF8U vv;
#pragma unroll
        for (int j = 0; j < 8; ++j) vv.u[j] = f2bf(wp[(size_t)j * 256]);
        ((uint4*)sB)[t] = vv.q;
      }
      __syncthreads();
      bf16x8 a = cvt8(&sAgg[(wrow + l15) * ASTR + kc * 32 + quad * 8], rs);
#pragma unroll
      for (int ns = 0; ns < 16; ++ns) {
        BF8U b8; b8.q = ((const uint4*)sB)[ns * 64 + lane];
        acc[ns] = __builtin_amdgcn_mfma_f32_16x16x32_bf16(a, b8.v, acc[ns], 0, 0, 0);
      }
      __syncthreads();
    }
  }
  {
    int row = m0 + wrow + l15;
    if (row >= NODES) row = NODES - 1;
    for (int kc = 0; kc < 8; ++kc) {
      for (int t = tid; t < 1024; t += ABLK) {
        int ln = t & 63, nc = t >> 6;
        const float* wp = sw + (size_t)(kc * 32 + (ln >> 4) * 8) * 256 + nc * 16 + (ln & 15);
        BF8U vv;
#pragma unroll
        for (int j = 0; j < 8; ++j) vv.u[j] = f2bf(wp[(size_t)j * 256]);
        ((uint4*)sB)[t] = vv.q;
      }
      __syncthreads();
      bf16x8 a = cvt8(x + (size_t)row * FEAT + kc * 32 + quad * 8, 1.0f);
#pragma unroll
      for (int ns = 0; ns < 16; ++ns) {
        BF8U b8; b8.q = ((const uint4*)sB)[ns * 64 + lane];
        acc[ns] = __builtin_amdgcn_mfma_f32_16x16x32_bf16(a, b8.v, acc[ns], 0, 0, 0);
      }
      __syncthreads();
    }
  }
#pragma unroll
  for (int i = 0; i < 4; ++i) {
    int row = m0 + wrow + quad * 4 + i;
    if (row < NODES) {
      float* op = out + (size_t)row * FEAT;
#pragma unroll
      for (int ns = 0; ns < 16; ++ns) {
        int col = ns * 16 + l15;
        op[col] = fmaxf(acc[ns][i] + bias[col], 0.0f);
      }
    }
  }
}

// ===========================================================================
extern "C" void kernel_launch(void* const* d_in, const int* in_sizes, int n_in,
                              void* d_out, int out_size, void* d_ws, size_t ws_size,
                              hipStream_t stream) {
  const float* x    = (const float*)d_in[0];
  const int*   src  = (const int*)d_in[1];
  const int*   dst  = (const int*)d_in[2];
  const float* w    = (const float*)d_in[3];
  const float* sw   = (const float*)d_in[4];
  const float* bias = (const float*)d_in[5];
  float*       out  = (float*)d_out;
  char* ws = (char*)d_ws;

  // ws: bpk 655360 | cnt 800000 | off 800016 | cur 800000 | epk 1280000
  //     | agg bf16 [4][N][256] 102400000  => NEED = 106,735,376
  const size_t NEED = 106735376;
  if (ws_size >= NEED) {
    unsigned short* bpk = (unsigned short*)ws;
    unsigned* cnt = (unsigned*)(ws + 655360);
    unsigned* off = (unsigned*)(ws + 1455360);
    unsigned* cur = (unsigned*)(ws + 2255376);
    unsigned* epk = (unsigned*)(ws + 3055376);
    unsigned short* agg = (unsigned short*)(ws + 4335376);

    zero_kernel<<<(NB + 255) / 256, 256, 0, stream>>>(cnt);
    count_kernel<<<(NEDGE + 255) / 256, 256, 0, stream>>>(dst, cnt);
    scan_kernel<<<1, 1024, 0, stream>>>(cnt, off, cur);
    fill_kernel<<<(NEDGE + 255) / 256, 256, 0, stream>>>(src, dst, cur, epk);
    prepack_kernel<<<160, 256, 0, stream>>>(w, sw, bpk);
    gather_kernel<<<(NODES + 3) / 4, 256, 0, stream>>>(x, off, epk, agg);
    gemm_kernel<<<dim3(391, 2), 256, 0, stream>>>(agg, x, bpk, bias, out);
  } else {
    rgcn_fallback<<<391, ABLK, 0, stream>>>(x, src, dst, w, sw, bias, out);
  }
}

// Round 8
// 321.317 us; speedup vs baseline: 2.6166x; 2.3610x over previous
//
#include <hip/hip_runtime.h>

#define NODES 50000
#define FEAT  256
#define RELS  4
#define EDGES 80000
#define NEDGE (RELS * EDGES)      // 320000
#define NB    (RELS * NODES)      // 200000 CSR buckets
#define NBSC  196                 // ceil(NB / 1024) scan blocks
#define KSTEPS 40                 // K = 1280 = 40 * 32
#define CHUNKEL ((size_t)NODES * FEAT)

typedef __bf16 bf16x8  __attribute__((ext_vector_type(8)));
typedef float  floatx4 __attribute__((ext_vector_type(4)));

struct BF8U { union { unsigned short u[8]; bf16x8 v; uint4 q; }; };

static __device__ __forceinline__ unsigned short f2bf(float f) {
  union { float f; unsigned u; } v; v.f = f;
  unsigned r = v.u + 0x7FFFu + ((v.u >> 16) & 1u);   // RNE
  return (unsigned short)(r >> 16);
}
static __device__ __forceinline__ bf16x8 cvt8(const float* p, float s) {
  float4 a = ((const float4*)p)[0], b = ((const float4*)p)[1];
  BF8U r;
  r.u[0] = f2bf(a.x * s); r.u[1] = f2bf(a.y * s);
  r.u[2] = f2bf(a.z * s); r.u[3] = f2bf(a.w * s);
  r.u[4] = f2bf(b.x * s); r.u[5] = f2bf(b.y * s);
  r.u[6] = f2bf(b.z * s); r.u[7] = f2bf(b.w * s);
  return r.v;
}

// ===========================================================================
// Setup: CSR by bucket b = r*NODES + dst
__global__ __launch_bounds__(256) void zero_kernel(unsigned* __restrict__ cnt) {
  int i = blockIdx.x * 256 + threadIdx.x;
  if (i < NB) cnt[i] = 0u;
}

__global__ __launch_bounds__(256) void count_kernel(const int* __restrict__ dst,
                                                    unsigned* __restrict__ cnt) {
  int e = blockIdx.x * 256 + threadIdx.x;
  if (e < NEDGE) atomicAdd(&cnt[(e / EDGES) * NODES + dst[e]], 1u);
}

// --- hierarchical exclusive scan (3 coalesced passes) ----------------------
__global__ __launch_bounds__(256) void scan1_kernel(const unsigned* __restrict__ cnt,
                                                    unsigned* __restrict__ bsum) {
  __shared__ unsigned red[4];
  int t = threadIdx.x;
  int i = blockIdx.x * 1024 + t * 4;
  unsigned s = 0;
  if (i + 3 < NB) {
    uint4 v = *(const uint4*)(cnt + i);
    s = v.x + v.y + v.z + v.w;
  } else {
    for (int j = 0; j < 4; ++j) if (i + j < NB) s += cnt[i + j];
  }
  for (int o = 32; o > 0; o >>= 1) s += __shfl_down(s, o);
  if ((t & 63) == 0) red[t >> 6] = s;
  __syncthreads();
  if (t == 0) bsum[blockIdx.x] = red[0] + red[1] + red[2] + red[3];
}

__global__ __launch_bounds__(256) void scan2_kernel(unsigned* __restrict__ bsum) {
  __shared__ unsigned sa[256], sb[256];
  int t = threadIdx.x;
  unsigned v = (t < NBSC) ? bsum[t] : 0u;
  sa[t] = v;
  __syncthreads();
  unsigned* pin = sa; unsigned* pout = sb;
  for (int d = 1; d < 256; d <<= 1) {
    pout[t] = pin[t] + ((t >= d) ? pin[t - d] : 0u);
    __syncthreads();
    unsigned* tmp = pin; pin = pout; pout = tmp;
  }
  if (t < NBSC) bsum[t] = pin[t] - v;          // exclusive base per scan-block
}

__global__ __launch_bounds__(256) void scan3_kernel(const unsigned* __restrict__ cnt,
                                                    const unsigned* __restrict__ bsum,
                                                    unsigned* __restrict__ off,
                                                    unsigned* __restrict__ cur) {
  __shared__ unsigned sa[256], sb[256];
  int t = threadIdx.x;
  int i = blockIdx.x * 1024 + t * 4;
  uint4 v = {0u, 0u, 0u, 0u};
  if (i + 3 < NB) {
    v = *(const uint4*)(cnt + i);
  } else {
    unsigned tmp[4] = {0u, 0u, 0u, 0u};
    for (int j = 0; j < 4; ++j) if (i + j < NB) tmp[j] = cnt[i + j];
    v.x = tmp[0]; v.y = tmp[1]; v.z = tmp[2]; v.w = tmp[3];
  }
  unsigned s = v.x + v.y + v.z + v.w;
  sa[t] = s;
  __syncthreads();
  unsigned* pin = sa; unsigned* pout = sb;
  for (int d = 1; d < 256; d <<= 1) {
    pout[t] = pin[t] + ((t >= d) ? pin[t - d] : 0u);
    __syncthreads();
    unsigned* tmp = pin; pin = pout; pout = tmp;
  }
  unsigned base = bsum[blockIdx.x] + pin[t] - s;   // global exclusive prefix
  uint4 o;
  o.x = base; o.y = o.x + v.x; o.z = o.y + v.y; o.w = o.z + v.z;
  if (i + 3 < NB) {
    *(uint4*)(off + i) = o;
    *(uint4*)(cur + i) = o;
  } else {
    unsigned oo[4] = {o.x, o.y, o.z, o.w};
    for (int j = 0; j < 4; ++j) if (i + j < NB) { off[i + j] = oo[j]; cur[i + j] = oo[j]; }
  }
  if (blockIdx.x == 0 && t == 0) off[NB] = NEDGE;  // total is statically known
}

__global__ __launch_bounds__(256) void fill_kernel(const int* __restrict__ src,
                                                   const int* __restrict__ dst,
                                                   unsigned* __restrict__ cur,
                                                   unsigned* __restrict__ epk) {
  int e = blockIdx.x * 256 + threadIdx.x;
  if (e < NEDGE) {
    int r = e / EDGES;
    unsigned pos = atomicAdd(&cur[r * NODES + dst[e]], 1u);
    epk[pos] = (unsigned)src[e];
  }
}

// W (f32) -> bf16 fragment order; uint4 slot g = kc*1024 + nc*64 + lane:
// val j = B[kc*32 + (lane>>4)*8 + j][nc*16 + (lane&15)], B = [W0;W1;W2;W3;Wself]
__global__ __launch_bounds__(256) void prepack_kernel(const float* __restrict__ w,
                                                      const float* __restrict__ sw,
                                                      unsigned short* __restrict__ bpk) {
  int t = blockIdx.x * 256 + threadIdx.x;      // [0, 40960)
  int ln = t & 63, nc = (t >> 6) & 15, kc = t >> 10;
  int col = nc * 16 + (ln & 15);
  int row0 = kc * 32 + (ln >> 4) * 8;
  BF8U vv;
#pragma unroll
  for (int j = 0; j < 8; ++j) {
    int gk = row0 + j;
    int c = gk >> 8, kr = gk & 255;
    const float* sp = (c < 4) ? (w + (size_t)c * 65536) : sw;
    vv.u[j] = f2bf(sp[(size_t)kr * 256 + col]);
  }
  ((uint4*)bpk)[t] = vv.q;
}

// ===========================================================================
// Gather: one wave per node; VGPR accumulation, no atomics, no LDS, no syncs.
__global__ __launch_bounds__(256) void gather_kernel(
    const float* __restrict__ x, const unsigned* __restrict__ off,
    const unsigned* __restrict__ epk, unsigned short* __restrict__ agg) {
  int n = blockIdx.x * 4 + (threadIdx.x >> 6);
  int lane = threadIdx.x & 63;
  if (n >= NODES) return;
  for (int r = 0; r < RELS; ++r) {
    unsigned b = (unsigned)r * NODES + n;
    unsigned lo = off[b], hi = off[b + 1];
    float4 acc = {0.f, 0.f, 0.f, 0.f};
    for (unsigned e = lo; e < hi; ++e) {
      int s = (int)epk[e];
      float4 v = *(const float4*)(x + (size_t)s * FEAT + lane * 4);
      acc.x += v.x; acc.y += v.y; acc.z += v.z; acc.w += v.w;
    }
    unsigned dg = hi - lo;
    float sc = 1.0f / (float)(dg ? dg : 1u);
    unsigned short o[4] = { f2bf(acc.x * sc), f2bf(acc.y * sc),
                            f2bf(acc.z * sc), f2bf(acc.w * sc) };
    *(uint2*)(agg + (size_t)b * FEAT + lane * 4) = *(const uint2*)o;
  }
}

// ===========================================================================
// GEMM: C[50000,256] = [agg0..3 | x] @ Bpk + bias, relu. LDS-free.
// 782 blocks (391 x 2) x 256 thr = 4 waves; wave tile 64x64 (4x4 MFMA).
__global__ __launch_bounds__(256) void gemm_kernel(
    const unsigned short* __restrict__ agg, const float* __restrict__ x,
    const unsigned short* __restrict__ bpk, const float* __restrict__ bias,
    float* __restrict__ out) {
  int lane = threadIdx.x & 63, wave = threadIdx.x >> 6;
  int quad = lane >> 4, l15 = lane & 15;
  int m0 = blockIdx.x * 128 + (wave >> 1) * 64;
  int nbase = blockIdx.y * 8 + (wave & 1) * 4;      // nc index base
  int n0 = nbase * 16;

  int rows[4];
#pragma unroll
  for (int ms = 0; ms < 4; ++ms) {
    int r = m0 + ms * 16 + l15;
    rows[ms] = (r < NODES) ? r : (NODES - 1);       // dup; stores guarded
  }

  floatx4 acc[4][4] = {};
  const uint4* bp4 = (const uint4*)bpk;

  for (int kc = 0; kc < KSTEPS; ++kc) {
    int c = kc >> 3;
    int kk = (kc & 7) * 32 + quad * 8;
    bf16x8 a[4], b[4];
    if (c < 4) {
      const unsigned short* ab = agg + (size_t)c * CHUNKEL;
#pragma unroll
      for (int ms = 0; ms < 4; ++ms) {
        BF8U t; t.q = *(const uint4*)(ab + (size_t)rows[ms] * FEAT + kk);
        a[ms] = t.v;
      }
    } else {
#pragma unroll
      for (int ms = 0; ms < 4; ++ms)
        a[ms] = cvt8(x + (size_t)rows[ms] * FEAT + kk, 1.0f);
    }
#pragma unroll
    for (int ns = 0; ns < 4; ++ns) {
      BF8U t; t.q = bp4[(size_t)kc * 1024 + (nbase + ns) * 64 + lane];
      b[ns] = t.v;
    }
#pragma unroll
    for (int ms = 0; ms < 4; ++ms)
#pragma unroll
      for (int ns = 0; ns < 4; ++ns)
        acc[ms][ns] = __builtin_amdgcn_mfma_f32_16x16x32_bf16(a[ms], b[ns], acc[ms][ns], 0, 0, 0);
  }

  // epilogue: C/D row = quad*4 + i, col = l15 (proven)
#pragma unroll
  for (int ms = 0; ms < 4; ++ms)
#pragma unroll
    for (int i = 0; i < 4; ++i) {
      int row = m0 + ms * 16 + quad * 4 + i;
      if (row < NODES) {
        float* op = out + (size_t)row * FEAT + n0;
#pragma unroll
        for (int ns = 0; ns < 4; ++ns) {
          int col = ns * 16 + l15;
          op[col] = fmaxf(acc[ms][ns][i] + bias[n0 + col], 0.0f);
        }
      }
    }
}

// ===========================================================================
// Fallback (R5's proven monolith) — only if ws_size too small.
#define AROWS 128
#define ASTR  260
#define ABLK  512

__global__ __launch_bounds__(ABLK) void rgcn_fallback(
    const float* __restrict__ x, const int* __restrict__ src,
    const int* __restrict__ dst, const float* __restrict__ w,
    const float* __restrict__ sw, const float* __restrict__ bias,
    float* __restrict__ out) {
  __shared__ float sAgg[AROWS * ASTR];
  __shared__ unsigned short sB[8192];
  __shared__ unsigned sDeg[AROWS];
  const int tid = threadIdx.x, wave = tid >> 6, lane = tid & 63;
  const int quad = lane >> 4, l15 = lane & 15;
  const int m0 = blockIdx.x * AROWS;
  const int wrow = wave * 16;
  floatx4 acc[16] = {};
  const floatx4 fz = {0.f, 0.f, 0.f, 0.f};
  for (int r = 0; r < RELS; ++r) {
    for (int t = tid; t < (AROWS * ASTR) / 4; t += ABLK) ((floatx4*)sAgg)[t] = fz;
    if (tid < AROWS) sDeg[tid] = 0u;
    __syncthreads();
    const int4* sr4 = (const int4*)(src + r * EDGES);
    const int4* dr4 = (const int4*)(dst + r * EDGES);
    for (int i0 = tid; i0 < 20480; i0 += ABLK) {
      int4 d4 = {-1, -1, -1, -1}, s4 = {0, 0, 0, 0};
      if (i0 < EDGES / 4) { d4 = dr4[i0]; s4 = sr4[i0]; }
      int dd[4] = {d4.x, d4.y, d4.z, d4.w};
      int ss[4] = {s4.x, s4.y, s4.z, s4.w};
#pragma unroll
      for (int j = 0; j < 4; ++j) {
        unsigned u = (unsigned)(dd[j] - m0);
        unsigned long long mb = __ballot(u < (unsigned)AROWS);
        while (mb) {
          int jl = (int)__ffsll(mb) - 1; mb &= mb - 1;
          int s = __shfl(ss[j], jl);
          int ul = __shfl((int)u, jl);
          if (lane == 0) atomicAdd(&sDeg[ul], 1u);
          const float* xp = x + (size_t)s * FEAT + lane;
          float* ap = sAgg + ul * ASTR + lane;
#pragma unroll
          for (int k = 0; k < 4; ++k) atomicAdd(ap + k * 64, xp[k * 64]);
        }
      }
    }
    __syncthreads();
    unsigned dg = sDeg[wrow + l15];
    float rs = 1.0f / (float)(dg ? dg : 1u);
    const float* Wc = w + (size_t)r * 65536;
    for (int kc = 0; kc < 8; ++kc) {
      for (int t = tid; t < 1024; t += ABLK) {
        int ln = t & 63, nc = t >> 6;
        const float* wp = Wc + (size_t)(kc * 32 + (ln >> 4) * 8) * 256 + nc * 16 + (ln & 15);
        BF8U vv;
#pragma unroll
        for (int j = 0; j < 8; ++j) vv.u[j] = f2bf(wp[(size_t)j * 256]);
        ((uint4*)sB)[t] = vv.q;
      }
      __syncthreads();
      bf16x8 a = cvt8(&sAgg[(wrow + l15) * ASTR + kc * 32 + quad * 8], rs);
#pragma unroll
      for (int ns = 0; ns < 16; ++ns) {
        BF8U b8; b8.q = ((const uint4*)sB)[ns * 64 + lane];
        acc[ns] = __builtin_amdgcn_mfma_f32_16x16x32_bf16(a, b8.v, acc[ns], 0, 0, 0);
      }
      __syncthreads();
    }
  }
  {
    int row = m0 + wrow + l15;
    if (row >= NODES) row = NODES - 1;
    for (int kc = 0; kc < 8; ++kc) {
      for (int t = tid; t < 1024; t += ABLK) {
        int ln = t & 63, nc = t >> 6;
        const float* wp = sw + (size_t)(kc * 32 + (ln >> 4) * 8) * 256 + nc * 16 + (ln & 15);
        BF8U vv;
#pragma unroll
        for (int j = 0; j < 8; ++j) vv.u[j] = f2bf(wp[(size_t)j * 256]);
        ((uint4*)sB)[t] = vv.q;
      }
      __syncthreads();
      bf16x8 a = cvt8(x + (size_t)row * FEAT + kc * 32 + quad * 8, 1.0f);
#pragma unroll
      for (int ns = 0; ns < 16; ++ns) {
        BF8U b8; b8.q = ((const uint4*)sB)[ns * 64 + lane];
        acc[ns] = __builtin_amdgcn_mfma_f32_16x16x32_bf16(a, b8.v, acc[ns], 0, 0, 0);
      }
      __syncthreads();
    }
  }
#pragma unroll
  for (int i = 0; i < 4; ++i) {
    int row = m0 + wrow + quad * 4 + i;
    if (row < NODES) {
      float* op = out + (size_t)row * FEAT;
#pragma unroll
      for (int ns = 0; ns < 16; ++ns) {
        int col = ns * 16 + l15;
        op[col] = fmaxf(acc[ns][i] + bias[col], 0.0f);
      }
    }
  }
}

// ===========================================================================
extern "C" void kernel_launch(void* const* d_in, const int* in_sizes, int n_in,
                              void* d_out, int out_size, void* d_ws, size_t ws_size,
                              hipStream_t stream) {
  const float* x    = (const float*)d_in[0];
  const int*   src  = (const int*)d_in[1];
  const int*   dst  = (const int*)d_in[2];
  const float* w    = (const float*)d_in[3];
  const float* sw   = (const float*)d_in[4];
  const float* bias = (const float*)d_in[5];
  float*       out  = (float*)d_out;
  char* ws = (char*)d_ws;

  // ws: bpk 655360 | cnt 800000 | off 800016 | cur 800000 | epk 1280000
  //     | bsum 784(+pad) | agg bf16 [4][N][256] 102400000
  const size_t NEED = 106736400;
  if (ws_size >= NEED) {
    unsigned short* bpk = (unsigned short*)ws;
    unsigned* cnt  = (unsigned*)(ws + 655360);
    unsigned* off  = (unsigned*)(ws + 1455360);
    unsigned* cur  = (unsigned*)(ws + 2255376);
    unsigned* epk  = (unsigned*)(ws + 3055376);
    unsigned* bsum = (unsigned*)(ws + 4335376);
    unsigned short* agg = (unsigned short*)(ws + 4336400);

    zero_kernel<<<(NB + 255) / 256, 256, 0, stream>>>(cnt);
    count_kernel<<<(NEDGE + 255) / 256, 256, 0, stream>>>(dst, cnt);
    scan1_kernel<<<NBSC, 256, 0, stream>>>(cnt, bsum);
    scan2_kernel<<<1, 256, 0, stream>>>(bsum);
    scan3_kernel<<<NBSC, 256, 0, stream>>>(cnt, bsum, off, cur);
    fill_kernel<<<(NEDGE + 255) / 256, 256, 0, stream>>>(src, dst, cur, epk);
    prepack_kernel<<<160, 256, 0, stream>>>(w, sw, bpk);
    gather_kernel<<<(NODES + 3) / 4, 256, 0, stream>>>(x, off, epk, agg);
    gemm_kernel<<<dim3(391, 2), 256, 0, stream>>>(agg, x, bpk, bias, out);
  } else {
    rgcn_fallback<<<391, ABLK, 0, stream>>>(x, src, dst, w, sw, bias, out);
  }
}

// Round 9
// 313.470 us; speedup vs baseline: 2.6821x; 1.0250x over previous
//
#include <hip/hip_runtime.h>

#define NODES 50000
#define FEAT  256
#define RELS  4
#define EDGES 80000
#define NEDGE (RELS * EDGES)      // 320000
#define NB    (RELS * NODES)      // 200000 CSR buckets
#define NBSC  196                 // ceil(NB / 1024) scan blocks
#define KSTEPS 40                 // K = 1280 = 40 * 32
#define CHUNKEL ((size_t)NODES * FEAT)

typedef __bf16 bf16x8  __attribute__((ext_vector_type(8)));
typedef float  floatx4 __attribute__((ext_vector_type(4)));

struct BF8U { union { unsigned short u[8]; bf16x8 v; uint4 q; }; };

static __device__ __forceinline__ unsigned short f2bf(float f) {
  union { float f; unsigned u; } v; v.f = f;
  unsigned r = v.u + 0x7FFFu + ((v.u >> 16) & 1u);   // RNE
  return (unsigned short)(r >> 16);
}
static __device__ __forceinline__ bf16x8 cvt8(const float* p, float s) {
  float4 a = ((const float4*)p)[0], b = ((const float4*)p)[1];
  BF8U r;
  r.u[0] = f2bf(a.x * s); r.u[1] = f2bf(a.y * s);
  r.u[2] = f2bf(a.z * s); r.u[3] = f2bf(a.w * s);
  r.u[4] = f2bf(b.x * s); r.u[5] = f2bf(b.y * s);
  r.u[6] = f2bf(b.z * s); r.u[7] = f2bf(b.w * s);
  return r.v;
}

// ===========================================================================
// Setup: CSR by bucket b = r*NODES + dst
__global__ __launch_bounds__(256) void zero_kernel(unsigned* __restrict__ cnt) {
  int i = blockIdx.x * 256 + threadIdx.x;
  if (i < NB) cnt[i] = 0u;
}

__global__ __launch_bounds__(256) void count_kernel(const int* __restrict__ dst,
                                                    unsigned* __restrict__ cnt) {
  int e = blockIdx.x * 256 + threadIdx.x;
  if (e < NEDGE) atomicAdd(&cnt[(e / EDGES) * NODES + dst[e]], 1u);
}

// --- hierarchical exclusive scan (3 coalesced passes) ----------------------
__global__ __launch_bounds__(256) void scan1_kernel(const unsigned* __restrict__ cnt,
                                                    unsigned* __restrict__ bsum) {
  __shared__ unsigned red[4];
  int t = threadIdx.x;
  int i = blockIdx.x * 1024 + t * 4;
  unsigned s = 0;
  if (i + 3 < NB) {
    uint4 v = *(const uint4*)(cnt + i);
    s = v.x + v.y + v.z + v.w;
  } else {
    for (int j = 0; j < 4; ++j) if (i + j < NB) s += cnt[i + j];
  }
  for (int o = 32; o > 0; o >>= 1) s += __shfl_down(s, o);
  if ((t & 63) == 0) red[t >> 6] = s;
  __syncthreads();
  if (t == 0) bsum[blockIdx.x] = red[0] + red[1] + red[2] + red[3];
}

__global__ __launch_bounds__(256) void scan2_kernel(unsigned* __restrict__ bsum) {
  __shared__ unsigned sa[256], sb[256];
  int t = threadIdx.x;
  unsigned v = (t < NBSC) ? bsum[t] : 0u;
  sa[t] = v;
  __syncthreads();
  unsigned* pin = sa; unsigned* pout = sb;
  for (int d = 1; d < 256; d <<= 1) {
    pout[t] = pin[t] + ((t >= d) ? pin[t - d] : 0u);
    __syncthreads();
    unsigned* tmp = pin; pin = pout; pout = tmp;
  }
  if (t < NBSC) bsum[t] = pin[t] - v;          // exclusive base per scan-block
}

__global__ __launch_bounds__(256) void scan3_kernel(const unsigned* __restrict__ cnt,
                                                    const unsigned* __restrict__ bsum,
                                                    unsigned* __restrict__ off,
                                                    unsigned* __restrict__ cur) {
  __shared__ unsigned sa[256], sb[256];
  int t = threadIdx.x;
  int i = blockIdx.x * 1024 + t * 4;
  uint4 v = {0u, 0u, 0u, 0u};
  if (i + 3 < NB) {
    v = *(const uint4*)(cnt + i);
  } else {
    unsigned tmp[4] = {0u, 0u, 0u, 0u};
    for (int j = 0; j < 4; ++j) if (i + j < NB) tmp[j] = cnt[i + j];
    v.x = tmp[0]; v.y = tmp[1]; v.z = tmp[2]; v.w = tmp[3];
  }
  unsigned s = v.x + v.y + v.z + v.w;
  sa[t] = s;
  __syncthreads();
  unsigned* pin = sa; unsigned* pout = sb;
  for (int d = 1; d < 256; d <<= 1) {
    pout[t] = pin[t] + ((t >= d) ? pin[t - d] : 0u);
    __syncthreads();
    unsigned* tmp = pin; pin = pout; pout = tmp;
  }
  unsigned base = bsum[blockIdx.x] + pin[t] - s;   // global exclusive prefix
  uint4 o;
  o.x = base; o.y = o.x + v.x; o.z = o.y + v.y; o.w = o.z + v.z;
  if (i + 3 < NB) {
    *(uint4*)(off + i) = o;
    *(uint4*)(cur + i) = o;
  } else {
    unsigned oo[4] = {o.x, o.y, o.z, o.w};
    for (int j = 0; j < 4; ++j) if (i + j < NB) { off[i + j] = oo[j]; cur[i + j] = oo[j]; }
  }
  if (blockIdx.x == 0 && t == 0) off[NB] = NEDGE;  // total is statically known
}

__global__ __launch_bounds__(256) void fill_kernel(const int* __restrict__ src,
                                                   const int* __restrict__ dst,
                                                   unsigned* __restrict__ cur,
                                                   unsigned* __restrict__ epk) {
  int e = blockIdx.x * 256 + threadIdx.x;
  if (e < NEDGE) {
    int r = e / EDGES;
    unsigned pos = atomicAdd(&cur[r * NODES + dst[e]], 1u);
    epk[pos] = (unsigned)src[e];
  }
}

// W (f32) -> bf16 fragment order; uint4 slot g = kc*1024 + nc*64 + lane:
// val j = B[kc*32 + (lane>>4)*8 + j][nc*16 + (lane&15)], B = [W0;W1;W2;W3;Wself]
__global__ __launch_bounds__(256) void prepack_kernel(const float* __restrict__ w,
                                                      const float* __restrict__ sw,
                                                      unsigned short* __restrict__ bpk) {
  int t = blockIdx.x * 256 + threadIdx.x;      // [0, 40960)
  int ln = t & 63, nc = (t >> 6) & 15, kc = t >> 10;
  int col = nc * 16 + (ln & 15);
  int row0 = kc * 32 + (ln >> 4) * 8;
  BF8U vv;
#pragma unroll
  for (int j = 0; j < 8; ++j) {
    int gk = row0 + j;
    int c = gk >> 8, kr = gk & 255;
    const float* sp = (c < 4) ? (w + (size_t)c * 65536) : sw;
    vv.u[j] = f2bf(sp[(size_t)kr * 256 + col]);
  }
  ((uint4*)bpk)[t] = vv.q;
}

// ===========================================================================
// Gather v2: one wave per (relation,node) bucket -> 200K waves of TLP.
// Edge loop unrolled x2 for dual outstanding row loads. No atomics/LDS/syncs.
__global__ __launch_bounds__(256) void gather_kernel(
    const float* __restrict__ x, const unsigned* __restrict__ off,
    const unsigned* __restrict__ epk, unsigned short* __restrict__ agg) {
  int b = blockIdx.x * 4 + (threadIdx.x >> 6);   // bucket id in [0, NB)
  int lane = threadIdx.x & 63;
  if (b >= NB) return;
  unsigned lo = off[b], hi = off[b + 1];
  float4 acc = {0.f, 0.f, 0.f, 0.f};
  unsigned e = lo;
  for (; e + 2 <= hi; e += 2) {
    int s0 = (int)epk[e], s1 = (int)epk[e + 1];
    float4 v0 = *(const float4*)(x + (size_t)s0 * FEAT + lane * 4);
    float4 v1 = *(const float4*)(x + (size_t)s1 * FEAT + lane * 4);
    acc.x += v0.x + v1.x; acc.y += v0.y + v1.y;
    acc.z += v0.z + v1.z; acc.w += v0.w + v1.w;
  }
  if (e < hi) {
    int s = (int)epk[e];
    float4 v = *(const float4*)(x + (size_t)s * FEAT + lane * 4);
    acc.x += v.x; acc.y += v.y; acc.z += v.z; acc.w += v.w;
  }
  unsigned dg = hi - lo;
  float sc = 1.0f / (float)(dg ? dg : 1u);
  unsigned short o[4] = { f2bf(acc.x * sc), f2bf(acc.y * sc),
                          f2bf(acc.z * sc), f2bf(acc.w * sc) };
  *(uint2*)(agg + (size_t)b * FEAT + lane * 4) = *(const uint2*)o;
}

// ===========================================================================
// GEMM v2: C[50000,256] = [agg0..3 | x] @ Bpk + bias, relu.
// Tile 64 rows x 256 cols per block (grid 782): A read from HBM exactly once.
// 4 waves; wave w owns cols [w*64, w*64+64). Register-ping-pong k-loop.
__global__ __launch_bounds__(256) void gemm_kernel(
    const unsigned short* __restrict__ agg, const float* __restrict__ x,
    const unsigned short* __restrict__ bpk, const float* __restrict__ bias,
    float* __restrict__ out) {
  int lane = threadIdx.x & 63, wave = threadIdx.x >> 6;
  int quad = lane >> 4, l15 = lane & 15;
  int m0 = blockIdx.x * 64;
  int nbase = wave * 4;                      // nc index base (cols wave*64..)

  int rows[4];
#pragma unroll
  for (int ms = 0; ms < 4; ++ms) {
    int r = m0 + ms * 16 + l15;
    rows[ms] = (r < NODES) ? r : (NODES - 1);   // dup; stores guarded
  }

  floatx4 acc[4][4] = {};
  const uint4* bp4 = (const uint4*)bpk;

#define LOAD_A(kc, dst)                                                        \
  {                                                                            \
    int c_ = (kc) >> 3;                                                        \
    int kk_ = ((kc) & 7) * 32 + quad * 8;                                      \
    if (c_ < 4) {                                                              \
      const unsigned short* ab_ = agg + (size_t)c_ * CHUNKEL;                  \
      _Pragma("unroll") for (int ms = 0; ms < 4; ++ms) {                       \
        BF8U t_; t_.q = *(const uint4*)(ab_ + (size_t)rows[ms] * FEAT + kk_);  \
        dst[ms] = t_.v;                                                        \
      }                                                                        \
    } else {                                                                   \
      _Pragma("unroll") for (int ms = 0; ms < 4; ++ms)                         \
        dst[ms] = cvt8(x + (size_t)rows[ms] * FEAT + kk_, 1.0f);               \
    }                                                                          \
  }
#define LOAD_B(kc, dst)                                                        \
  {                                                                            \
    _Pragma("unroll") for (int ns = 0; ns < 4; ++ns) {                         \
      BF8U t_; t_.q = bp4[(size_t)(kc) * 1024 + (nbase + ns) * 64 + lane];     \
      dst[ns] = t_.v;                                                          \
    }                                                                          \
  }
#define MFMA16(af, bf)                                                         \
  _Pragma("unroll") for (int ms = 0; ms < 4; ++ms)                             \
    _Pragma("unroll") for (int ns = 0; ns < 4; ++ns)                           \
      acc[ms][ns] = __builtin_amdgcn_mfma_f32_16x16x32_bf16(af[ms], bf[ns],    \
                                                            acc[ms][ns], 0, 0, 0);

  bf16x8 a0[4], b0[4], a1[4], b1[4];
  LOAD_A(0, a0);
  LOAD_B(0, b0);
  for (int kc = 0; kc < KSTEPS; kc += 2) {
    LOAD_A(kc + 1, a1);
    LOAD_B(kc + 1, b1);
    MFMA16(a0, b0);
    if (kc + 2 < KSTEPS) {
      LOAD_A(kc + 2, a0);
      LOAD_B(kc + 2, b0);
    }
    MFMA16(a1, b1);
  }
#undef LOAD_A
#undef LOAD_B
#undef MFMA16

  // epilogue: C/D row = quad*4 + i, col = l15 (proven)
#pragma unroll
  for (int ms = 0; ms < 4; ++ms)
#pragma unroll
    for (int i = 0; i < 4; ++i) {
      int row = m0 + ms * 16 + quad * 4 + i;
      if (row < NODES) {
        float* op = out + (size_t)row * FEAT + wave * 64;
#pragma unroll
        for (int ns = 0; ns < 4; ++ns) {
          int col = ns * 16 + l15;
          op[col] = fmaxf(acc[ms][ns][i] + bias[wave * 64 + col], 0.0f);
        }
      }
    }
}

// ===========================================================================
// Fallback (R5's proven monolith) — only if ws_size too small.
#define AROWS 128
#define ASTR  260
#define ABLK  512

__global__ __launch_bounds__(ABLK) void rgcn_fallback(
    const float* __restrict__ x, const int* __restrict__ src,
    const int* __restrict__ dst, const float* __restrict__ w,
    const float* __restrict__ sw, const float* __restrict__ bias,
    float* __restrict__ out) {
  __shared__ float sAgg[AROWS * ASTR];
  __shared__ unsigned short sB[8192];
  __shared__ unsigned sDeg[AROWS];
  const int tid = threadIdx.x, wave = tid >> 6, lane = tid & 63;
  const int quad = lane >> 4, l15 = lane & 15;
  const int m0 = blockIdx.x * AROWS;
  const int wrow = wave * 16;
  floatx4 acc[16] = {};
  const floatx4 fz = {0.f, 0.f, 0.f, 0.f};
  for (int r = 0; r < RELS; ++r) {
    for (int t = tid; t < (AROWS * ASTR) / 4; t += ABLK) ((floatx4*)sAgg)[t] = fz;
    if (tid < AROWS) sDeg[tid] = 0u;
    __syncthreads();
    const int4* sr4 = (const int4*)(src + r * EDGES);
    const int4* dr4 = (const int4*)(dst + r * EDGES);
    for (int i0 = tid; i0 < 20480; i0 += ABLK) {
      int4 d4 = {-1, -1, -1, -1}, s4 = {0, 0, 0, 0};
      if (i0 < EDGES / 4) { d4 = dr4[i0]; s4 = sr4[i0]; }
      int dd[4] = {d4.x, d4.y, d4.z, d4.w};
      int ss[4] = {s4.x, s4.y, s4.z, s4.w};
#pragma unroll
      for (int j = 0; j < 4; ++j) {
        unsigned u = (unsigned)(dd[j] - m0);
        unsigned long long mb = __ballot(u < (unsigned)AROWS);
        while (mb) {
          int jl = (int)__ffsll(mb) - 1; mb &= mb - 1;
          int s = __shfl(ss[j], jl);
          int ul = __shfl((int)u, jl);
          if (lane == 0) atomicAdd(&sDeg[ul], 1u);
          const float* xp = x + (size_t)s * FEAT + lane;
          float* ap = sAgg + ul * ASTR + lane;
#pragma unroll
          for (int k = 0; k < 4; ++k) atomicAdd(ap + k * 64, xp[k * 64]);
        }
      }
    }
    __syncthreads();
    unsigned dg = sDeg[wrow + l15];
    float rs = 1.0f / (float)(dg ? dg : 1u);
    const float* Wc = w + (size_t)r * 65536;
    for (int kc = 0; kc < 8; ++kc) {
      for (int t = tid; t < 1024; t += ABLK) {
        int ln = t & 63, nc = t >> 6;
        const float* wp = Wc + (size_t)(kc * 32 + (ln >> 4) * 8) * 256 + nc * 16 + (ln & 15);
        BF8U vv;
#pragma unroll
        for (int j = 0; j < 8; ++j) vv.u[j] = f2bf(wp[(size_t)j * 256]);
        ((uint4*)sB)[t] = vv.q;
      }
      __syncthreads();
      bf16x8 a = cvt8(&sAgg[(wrow + l15) * ASTR + kc * 32 + quad * 8], rs);
#pragma unroll
      for (int ns = 0; ns < 16; ++ns) {
        BF8U b8; b8.q = ((const uint4*)sB)[ns * 64 + lane];
        acc[ns] = __builtin_amdgcn_mfma_f32_16x16x32_bf16(a, b8.v, acc[ns], 0, 0, 0);
      }
      __syncthreads();
    }
  }
  {
    int row = m0 + wrow + l15;
    if (row >= NODES) row = NODES - 1;
    for (int kc = 0; kc < 8; ++kc) {
      for (int t = tid; t < 1024; t += ABLK) {
        int ln = t & 63, nc = t >> 6;
        const float* wp = sw + (size_t)(kc * 32 + (ln >> 4) * 8) * 256 + nc * 16 + (ln & 15);
        BF8U vv;
#pragma unroll
        for (int j = 0; j < 8; ++j) vv.u[j] = f2bf(wp[(size_t)j * 256]);
        ((uint4*)sB)[t] = vv.q;
      }
      __syncthreads();
      bf16x8 a = cvt8(x + (size_t)row * FEAT + kc * 32 + quad * 8, 1.0f);
#pragma unroll
      for (int ns = 0; ns < 16; ++ns) {
        BF8U b8; b8.q = ((const uint4*)sB)[ns * 64 + lane];
        acc[ns] = __builtin_amdgcn_mfma_f32_16x16x32_bf16(a, b8.v, acc[ns], 0, 0, 0);
      }
      __syncthreads();
    }
  }
#pragma unroll
  for (int i = 0; i < 4; ++i) {
    int row = m0 + wrow + quad * 4 + i;
    if (row < NODES) {
      float* op = out + (size_t)row * FEAT;
#pragma unroll
      for (int ns = 0; ns < 16; ++ns) {
        int col = ns * 16 + l15;
        op[col] = fmaxf(acc[ns][i] + bias[col], 0.0f);
      }
    }
  }
}

// ===========================================================================
extern "C" void kernel_launch(void* const* d_in, const int* in_sizes, int n_in,
                              void* d_out, int out_size, void* d_ws, size_t ws_size,
                              hipStream_t stream) {
  const float* x    = (const float*)d_in[0];
  const int*   src  = (const int*)d_in[1];
  const int*   dst  = (const int*)d_in[2];
  const float* w    = (const float*)d_in[3];
  const float* sw   = (const float*)d_in[4];
  const float* bias = (const float*)d_in[5];
  float*       out  = (float*)d_out;
  char* ws = (char*)d_ws;

  // ws: bpk 655360 | cnt 800000 | off 800016 | cur 800000 | epk 1280000
  //     | bsum 784(+pad) | agg bf16 [4][N][256] 102400000
  const size_t NEED = 106736400;
  if (ws_size >= NEED) {
    unsigned short* bpk = (unsigned short*)ws;
    unsigned* cnt  = (unsigned*)(ws + 655360);
    unsigned* off  = (unsigned*)(ws + 1455360);
    unsigned* cur  = (unsigned*)(ws + 2255376);
    unsigned* epk  = (unsigned*)(ws + 3055376);
    unsigned* bsum = (unsigned*)(ws + 4335376);
    unsigned short* agg = (unsigned short*)(ws + 4336400);

    zero_kernel<<<(NB + 255) / 256, 256, 0, stream>>>(cnt);
    count_kernel<<<(NEDGE + 255) / 256, 256, 0, stream>>>(dst, cnt);
    scan1_kernel<<<NBSC, 256, 0, stream>>>(cnt, bsum);
    scan2_kernel<<<1, 256, 0, stream>>>(bsum);
    scan3_kernel<<<NBSC, 256, 0, stream>>>(cnt, bsum, off, cur);
    fill_kernel<<<(NEDGE + 255) / 256, 256, 0, stream>>>(src, dst, cur, epk);
    prepack_kernel<<<160, 256, 0, stream>>>(w, sw, bpk);
    gather_kernel<<<(NB + 3) / 4, 256, 0, stream>>>(x, off, epk, agg);
    gemm_kernel<<<(NODES + 63) / 64, 256, 0, stream>>>(agg, x, bpk, bias, out);
  } else {
    rgcn_fallback<<<391, ABLK, 0, stream>>>(x, src, dst, w, sw, bias, out);
  }
}